// Round 4
// baseline (1856.503 us; speedup 1.0000x reference)
//
#include <hip/hip_runtime.h>
#include <cstdint>

namespace {

typedef _Float16 half_t;
typedef half_t half8  __attribute__((ext_vector_type(8)));
typedef __fp16 fp16x2 __attribute__((ext_vector_type(2)));
typedef float  f32x4  __attribute__((ext_vector_type(4)));

constexpr int LSIDE = 64;   // lattice side
constexpr int HID   = 32;   // hidden size
constexpr int NB    = 16;   // batch elements per group (MFMA N dim)
constexpr int NG    = 2;    // independent groups per wave (latency hiding)

__device__ __forceinline__ half8 as_h8(uint4 u) { return __builtin_bit_cast(half8, u); }
__device__ __forceinline__ uint4 as_u4(half8 h) { return __builtin_bit_cast(uint4, h); }
__device__ __forceinline__ unsigned pk2(float a, float b) {
    fp16x2 t = __builtin_amdgcn_cvt_pkrtz(a, b);
    return __builtin_bit_cast(unsigned, t);
}
__device__ __forceinline__ float elu1(float v) {
    float e = __expf(v) - 1.f;
    return v > 0.f ? v : e;
}

#define MFMA(a, b, c) __builtin_amdgcn_mfma_f32_16x16x32_f16((a), (b), (c), 0, 0, 0)

// Layout (v_mfma_f32_16x16x32_f16), same as verified round-3 kernel:
//   A: lane holds A[row = l&15][k = 8*(l>>4)+e]
//   B: lane holds B[k = 8*(l>>4)+e][col = l&15]
//   C: lane holds C[row = 4*(l>>4)+c][col = l&15]
// A rows permuted so C of step s IS the B fragment of step s+1:
//   MFMA1 row rho -> j1 = 8*(rho>>2)+(rho&3); MFMA2 -> j1+4.

__device__ __forceinline__ void build_pre(
    const half8& A3a, const half8& A3b, const half8& A1v, const half8& A2v,
    unsigned aP, unsigned bP, unsigned onePair, const uint4& cv,
    f32x4& pre1, f32x4& pre2)
{
    f32x4 zc; zc[0] = 0.f; zc[1] = 0.f; zc[2] = 0.f; zc[3] = 0.f;
    uint4 b3u{aP, bP, onePair, 0u};
    const half8 B3 = as_h8(b3u);
    f32x4 q1 = MFMA(A3a, B3, zc);
    f32x4 q2 = MFMA(A3b, B3, zc);
    const half8 cvh = as_h8(cv);
    pre1 = MFMA(A1v, cvh, q1);
    pre2 = MFMA(A2v, cvh, q2);
}

__device__ __forceinline__ half8 elupack(const f32x4& a1, const f32x4& a2) {
    uint4 nb;
    nb.x = pk2(elu1(a1[0]), elu1(a1[1]));
    nb.y = pk2(elu1(a1[2]), elu1(a1[3]));
    nb.z = pk2(elu1(a2[0]), elu1(a2[1]));
    nb.w = pk2(elu1(a2[2]), elu1(a2[3]));
    return as_h8(nb);
}

__device__ __forceinline__ void outstep(const half8& Awd, const half8& hcB,
                                        const f32x4& dinit, unsigned xb, float& logp) {
    f32x4 od = MFMA(Awd, hcB, dinit);
    const float d = od[0];
    const float u = xb ? -d : d;                 // -dx
    logp -= __logf(1.f + __expf(u));
}

__device__ __forceinline__ unsigned pat(unsigned bit, unsigned gmask) {
    return (bit ? 0x3C000000u : 0x00003C00u) & gmask;
}

__global__ __launch_bounds__(64) void rnn2d_mfma2(
    const int*   __restrict__ x,     // [B, 64, 64]
    const float* __restrict__ Win,   // [4, 32]
    const float* __restrict__ WcH,   // [32, 32]
    const float* __restrict__ WcV,   // [32, 32]
    const float* __restrict__ bV,    // [32]
    const float* __restrict__ Wout,  // [32, 2]
    const float* __restrict__ bout,  // [2]
    float*       __restrict__ out)   // [B]
{
    const int l = threadIdx.x;
    const int r = l & 15;
    const int g = l >> 4;
    const int n = l & 15;
    const int bbase = blockIdx.x * (NB * NG);

    __shared__ uint4 cvs[NG][LSIDE * 64];   // 2 x 64KB vertical-carry fragments

    {
        const uint4 z{0u, 0u, 0u, 0u};
        for (int i = l; i < LSIDE * 64; i += 64) { cvs[0][i] = z; cvs[1][i] = z; }
    }

    // ---- constant A fragments (shared by both groups) ----
    const int j1 = 8 * (r >> 2) + (r & 3);
    const int j2 = j1 + 4;
    half8 A1h, A2h, A1v, A2v, A3a, A3b, Awd;
#pragma unroll
    for (int e = 0; e < 8; ++e) {
        const int k = 8 * g + e;
        A1h[e] = (half_t)WcH[k * HID + j1];
        A2h[e] = (half_t)WcH[k * HID + j2];
        A1v[e] = (half_t)WcV[k * HID + j1];
        A2v[e] = (half_t)WcV[k * HID + j2];
        float a3a = 0.f, a3b = 0.f;
        if (k < 4)       { a3a = Win[k * HID + j1]; a3b = Win[k * HID + j2]; }
        else if (k == 4) { a3a = bV[j1];            a3b = bV[j2]; }
        A3a[e] = (half_t)a3a;
        A3b[e] = (half_t)a3b;
        Awd[e] = (half_t)((r == 0) ? (Wout[k * 2 + 1] - Wout[k * 2 + 0]) : 0.f);
    }
    const float db = bout[1] - bout[0];
    f32x4 dinit; dinit[0] = db; dinit[1] = db; dinit[2] = db; dinit[3] = db;

    const unsigned gmask   = (g == 0) ? 0xFFFFFFFFu : 0u;
    const unsigned onePair = 0x00003C00u & gmask;   // f16 (1.0, 0)

    const int* xwA = x + (long)bbase * (LSIDE * LSIDE);
    const int* xwB = xwA + (long)NB * (LSIDE * LSIDE);

    __syncthreads();

    // spin prefetch registers (row 0)
    int xrA[NB], xrB[NB];
#pragma unroll
    for (int nn = 0; nn < NB; ++nn) {
        xrA[nn] = xwA[nn * (LSIDE * LSIDE) + l];
        xrB[nn] = xwB[nn * (LSIDE * LSIDE) + l];
    }

    unsigned long long rmA_prev = 0ull, rmB_prev = 0ull;
    float logpA = 0.f, logpB = 0.f;

    for (int row = 0; row < LSIDE; ++row) {
        // ---- build row masks (lane n holds batch-n bit row) ----
        unsigned long long rmA_cur = 0ull, rmB_cur = 0ull;
#pragma unroll
        for (int nn = 0; nn < NB; ++nn) {
            const unsigned long long balA = __ballot(xrA[nn] == 1);
            const unsigned long long balB = __ballot(xrB[nn] == 1);
            rmA_cur = (n == nn) ? balA : rmA_cur;
            rmB_cur = (n == nn) ? balB : rmB_cur;
        }
        if (row < LSIDE - 1) {
#pragma unroll
            for (int nn = 0; nn < NB; ++nn) {
                xrA[nn] = xwA[nn * (LSIDE * LSIDE) + (row + 1) * LSIDE + l];
                xrB[nn] = xwB[nn * (LSIDE * LSIDE) + (row + 1) * LSIDE + l];
            }
        }

        const bool fwd = ((row & 1) == 0);
        const int pstep = fwd ? 1 : -1;
        const int p0 = fwd ? 0 : (LSIDE - 1);
        const unsigned rowm = (row > 0) ? 0xFFFFFFFFu : 0u;

        half8 hcA, hcC;
        f32x4 p1A, p2A, p1B, p2B;
        uint4 cvNA, cvNB;
        unsigned xbA, xbB;

        // ---- prologue: s = 0 (hcarry = 0 -> acc == pre) and pre(1) ----
        {
            const unsigned bP0A = pat((unsigned)(rmA_prev >> p0) & 1u, gmask) & rowm;
            const unsigned bP0B = pat((unsigned)(rmB_prev >> p0) & 1u, gmask) & rowm;
            const uint4 cv0A = cvs[0][(p0 << 6) + l];
            const uint4 cv0B = cvs[1][(p0 << 6) + l];
            build_pre(A3a, A3b, A1v, A2v, 0u, bP0A, onePair, cv0A, p1A, p2A);
            build_pre(A3a, A3b, A1v, A2v, 0u, bP0B, onePair, cv0B, p1B, p2B);
            hcA = elupack(p1A, p2A);          // state(0) group A
            hcC = elupack(p1B, p2B);          // state(0) group B
            xbA = (unsigned)(rmA_cur >> p0) & 1u;
            xbB = (unsigned)(rmB_cur >> p0) & 1u;

            const int p1c = p0 + pstep;
            const uint4 cv1A = cvs[0][(p1c << 6) + l];
            const uint4 cv1B = cvs[1][(p1c << 6) + l];
            const unsigned bP1A = pat((unsigned)(rmA_prev >> p1c) & 1u, gmask) & rowm;
            const unsigned bP1B = pat((unsigned)(rmB_prev >> p1c) & 1u, gmask) & rowm;
            build_pre(A3a, A3b, A1v, A2v, pat(xbA, gmask), bP1A, onePair, cv1A, p1A, p2A);
            build_pre(A3a, A3b, A1v, A2v, pat(xbB, gmask), bP1B, onePair, cv1B, p1B, p2B);
            cvNA = cvs[0][((p1c + pstep) << 6) + l];   // cv for pre(2)
            cvNB = cvs[1][((p1c + pstep) << 6) + l];
        }

        int p = p0 + pstep;                   // column of step s

        // ---- steady-state: s = 1..62, branch-free ----
#pragma unroll 2
        for (int s = 1; s <= LSIDE - 2; ++s) {
            // recurrence (chain) — both groups interleave to hide latency
            f32x4 a1A = MFMA(A1h, hcA, p1A);
            f32x4 a2A = MFMA(A2h, hcA, p2A);
            f32x4 a1B = MFMA(A1h, hcC, p1B);
            f32x4 a2B = MFMA(A2h, hcC, p2B);

            // lagged output + vertical-carry store for step s-1
            outstep(Awd, hcA, dinit, xbA, logpA);
            outstep(Awd, hcC, dinit, xbB, logpB);
            cvs[0][((p - pstep) << 6) + l] = as_u4(hcA);
            cvs[1][((p - pstep) << 6) + l] = as_u4(hcC);

            // bits at col(s)
            const unsigned xnA = (unsigned)(rmA_cur >> p) & 1u;
            const unsigned xnB = (unsigned)(rmB_cur >> p) & 1u;

            // pre(s+1) using prefetched cv fragments
            const int pn = p + pstep;
            const unsigned bPnA = pat((unsigned)(rmA_prev >> pn) & 1u, gmask) & rowm;
            const unsigned bPnB = pat((unsigned)(rmB_prev >> pn) & 1u, gmask) & rowm;
            build_pre(A3a, A3b, A1v, A2v, pat(xnA, gmask), bPnA, onePair, cvNA, p1A, p2A);
            build_pre(A3a, A3b, A1v, A2v, pat(xnB, gmask), bPnB, onePair, cvNB, p1B, p2B);

            // prefetch cv for pre(s+2) (clamped; s=62 value unused)
            int pq = pn + pstep;
            pq = pq < 0 ? 0 : (pq > LSIDE - 1 ? LSIDE - 1 : pq);
            cvNA = cvs[0][(pq << 6) + l];
            cvNB = cvs[1][(pq << 6) + l];

            // elu + pack -> state(s) (chain tail)
            hcA = elupack(a1A, a2A);
            hcC = elupack(a1B, a2B);
            xbA = xnA;
            xbB = xnB;
            p += pstep;
        }

        // ---- epilogue: s = 63 ----
        {
            f32x4 a1A = MFMA(A1h, hcA, p1A);
            f32x4 a2A = MFMA(A2h, hcA, p2A);
            f32x4 a1B = MFMA(A1h, hcC, p1B);
            f32x4 a2B = MFMA(A2h, hcC, p2B);
            outstep(Awd, hcA, dinit, xbA, logpA);        // out(62)
            outstep(Awd, hcC, dinit, xbB, logpB);
            cvs[0][((p - pstep) << 6) + l] = as_u4(hcA);
            cvs[1][((p - pstep) << 6) + l] = as_u4(hcC);
            hcA = elupack(a1A, a2A);                     // state(63)
            hcC = elupack(a1B, a2B);
            const unsigned x63A = (unsigned)(rmA_cur >> p) & 1u;
            const unsigned x63B = (unsigned)(rmB_cur >> p) & 1u;
            outstep(Awd, hcA, dinit, x63A, logpA);       // out(63)
            outstep(Awd, hcC, dinit, x63B, logpB);
            cvs[0][(p << 6) + l] = as_u4(hcA);
            cvs[1][(p << 6) + l] = as_u4(hcC);
        }

        rmA_prev = rmA_cur;
        rmB_prev = rmB_cur;
    }

    if (l < NB) {
        out[bbase + l]      = 0.5f * logpA;
        out[bbase + NB + l] = 0.5f * logpB;
    }
}

} // namespace

extern "C" void kernel_launch(void* const* d_in, const int* in_sizes, int n_in,
                              void* d_out, int out_size, void* d_ws, size_t ws_size,
                              hipStream_t stream) {
    (void)n_in; (void)out_size; (void)d_ws; (void)ws_size;
    const int*   x    = (const int*)  d_in[0];
    const float* Win  = (const float*)d_in[1];
    const float* WcH  = (const float*)d_in[2];
    const float* WcV  = (const float*)d_in[3];
    const float* bV   = (const float*)d_in[4];
    const float* Wout = (const float*)d_in[5];
    const float* bout = (const float*)d_in[6];
    float*       out  = (float*)d_out;

    const int B = in_sizes[0] / (LSIDE * LSIDE);
    rnn2d_mfma2<<<B / (NB * NG), 64, 0, stream>>>(x, Win, WcH, WcV, bV, Wout, bout, out);
}

// Round 5
// 1058.454 us; speedup vs baseline: 1.7540x; 1.7540x over previous
//
#include <hip/hip_runtime.h>
#include <cstdint>

namespace {

typedef _Float16 half_t;
typedef half_t half8  __attribute__((ext_vector_type(8)));
typedef __fp16 fp16x2 __attribute__((ext_vector_type(2)));
typedef float  f32x4  __attribute__((ext_vector_type(4)));

constexpr int LSIDE = 64;   // lattice side
constexpr int HID   = 32;   // hidden size
constexpr int NB    = 16;   // batch elements per wave (MFMA N dim)
constexpr int SLOTS = 66;   // LDS column slots: col+1 for col in [-1, 64]

__device__ __forceinline__ half8 as_h8(uint4 u) { return __builtin_bit_cast(half8, u); }
__device__ __forceinline__ uint4 as_u4(half8 h) { return __builtin_bit_cast(uint4, h); }
__device__ __forceinline__ unsigned pk2(float a, float b) {
    fp16x2 t = __builtin_amdgcn_cvt_pkrtz(a, b);
    return __builtin_bit_cast(unsigned, t);
}
__device__ __forceinline__ float elu1(float v) {
    float e = __expf(v) - 1.f;
    return v > 0.f ? v : e;
}

#define MFMA(a, b, c) __builtin_amdgcn_mfma_f32_16x16x32_f16((a), (b), (c), 0, 0, 0)

// Layout (v_mfma_f32_16x16x32_f16), verified in round 3:
//   A: lane holds A[row = l&15][k = 8*(l>>4)+e]
//   B: lane holds B[k = 8*(l>>4)+e][col = l&15]
//   C: lane holds C[row = 4*(l>>4)+c][col = l&15]
// A rows permuted so C of step s IS the B fragment of step s+1:
//   MFMA1 row rho -> j1 = 8*(rho>>2)+(rho&3); MFMA2 -> j1+4.

__global__ __launch_bounds__(64) void rnn2d_mfma5(
    const int*   __restrict__ x,     // [B, 64, 64]
    const float* __restrict__ Win,   // [4, 32]
    const float* __restrict__ WcH,   // [32, 32]
    const float* __restrict__ WcV,   // [32, 32]
    const float* __restrict__ bV,    // [32]
    const float* __restrict__ Wout,  // [32, 2]
    const float* __restrict__ bout,  // [2]
    float*       __restrict__ out)   // [B]
{
    const int l = threadIdx.x;
    const int r = l & 15;
    const int g = l >> 4;
    const int n = l & 15;             // batch-in-wave (replicated across g-groups)
    const int bbase = blockIdx.x * NB;

    __shared__ uint4 cvs[SLOTS * 64];   // [slot = col+1][lane] f16x8 carry frags

    {
        const uint4 z{0u, 0u, 0u, 0u};
        for (int i = l; i < SLOTS * 64; i += 64) cvs[i] = z;
    }

    // ---- constant A fragments ----
    const int j1 = 8 * (r >> 2) + (r & 3);
    const int j2 = j1 + 4;
    half8 A1h, A2h, A1v, A2v, A3a, A3b, Awd;
#pragma unroll
    for (int e = 0; e < 8; ++e) {
        const int k = 8 * g + e;
        A1h[e] = (half_t)WcH[k * HID + j1];
        A2h[e] = (half_t)WcH[k * HID + j2];
        A1v[e] = (half_t)WcV[k * HID + j1];
        A2v[e] = (half_t)WcV[k * HID + j2];
        float a3a = 0.f, a3b = 0.f;
        if (k < 4)       { a3a = Win[k * HID + j1]; a3b = Win[k * HID + j2]; }
        else if (k == 4) { a3a = bV[j1];            a3b = bV[j2]; }
        A3a[e] = (half_t)a3a;
        A3b[e] = (half_t)a3b;
        Awd[e] = (half_t)((r == 0) ? (Wout[k * 2 + 1] - Wout[k * 2 + 0]) : 0.f);
    }
    const float db = bout[1] - bout[0];
    f32x4 dinit; dinit[0] = db; dinit[1] = db; dinit[2] = db; dinit[3] = db;
    f32x4 zc;    zc[0] = 0.f;  zc[1] = 0.f;  zc[2] = 0.f;  zc[3] = 0.f;

    const unsigned gm = (g == 0) ? 0x3C00u : 0u;     // f16 1.0 selector (per-lane)
    const float Cterm = __logf(1.f + __expf(db));    // s=0 garbage softplus term

    const int* xw = x + (long)bbase * (LSIDE * LSIDE);

    __syncthreads();

    int xr[NB];
#pragma unroll
    for (int nn = 0; nn < NB; ++nn) xr[nn] = xw[nn * (LSIDE * LSIDE) + l];

    unsigned long long rmCur = 0ull;
    float logp = 0.f;

    uint4 cvA[8], cvB[8], cvDummy{0u,0u,0u,0u};
    (void)cvDummy;

    for (int row = 0; row < LSIDE; ++row) {
        const unsigned long long rmPrev = rmCur;
        {
            unsigned long long rm = 0ull;
#pragma unroll
            for (int nn = 0; nn < NB; ++nn) {
                const unsigned long long bal = __ballot(xr[nn] == 1);
                rm = (n == nn) ? bal : rm;
            }
            rmCur = rm;
        }
        {
            const int nrow = (row < LSIDE - 1) ? row + 1 : LSIDE - 1;
#pragma unroll
            for (int nn = 0; nn < NB; ++nn)
                xr[nn] = xw[nn * (LSIDE * LSIDE) + nrow * LSIDE + l];
        }

        const int dir = (row & 1) ? -1 : 1;
        int col = (row & 1) ? (LSIDE - 1) : 0;
        const unsigned grow = (row > 0) ? gm : 0u;   // masks row-(-1) one-hot term

        // chunk-0 cv loads (prev row's carries; compiler inserts the lgkm wait)
#pragma unroll
        for (int i = 0; i < 8; ++i) cvA[i] = cvs[(col + i * dir + 1) * 64 + l];

        // pre(0): no left term (aP = 0)
        f32x4 pre1, pre2;
        {
            const unsigned bitU = (unsigned)(rmPrev >> col) & 1u;
            uint4 b3u{0u, grow << (bitU << 4), gm, 0u};
            f32x4 q1 = MFMA(A3a, as_h8(b3u), zc);
            f32x4 q2 = MFMA(A3b, as_h8(b3u), zc);
            pre1 = MFMA(A1v, as_h8(cvA[0]), q1);
            pre2 = MFMA(A2v, as_h8(cvA[0]), q2);
        }

        uint4 hz{0u, 0u, 0u, 0u};
        half8 hc = as_h8(hz);            // state(-1) = 0
        unsigned sign32 = 0u;            // sign bit for lagged out(-1) (garbage, comp'd)

#define STEP(CVUSE, PREFDST, DOPREF, DOPRE)                                    \
  {                                                                            \
    f32x4 a1 = MFMA(A1h, hc, pre1);                                            \
    f32x4 a2 = MFMA(A2h, hc, pre2);                                            \
    f32x4 od = MFMA(Awd, hc, dinit);                                           \
    cvs[(col - dir + 1) * 64 + l] = as_u4(hc);                                 \
    const float du = __int_as_float(__float_as_int(od[0]) ^ sign32);           \
    logp -= __logf(1.f + __expf(du));                                          \
    const unsigned bitL = (unsigned)(rmCur >> col) & 1u;                       \
    if (DOPRE) {                                                               \
      const unsigned bitU = (unsigned)(rmPrev >> (col + dir)) & 1u;            \
      uint4 b3u{gm << (bitL << 4), grow << (bitU << 4), gm, 0u};               \
      f32x4 q1 = MFMA(A3a, as_h8(b3u), zc);                                    \
      f32x4 q2 = MFMA(A3b, as_h8(b3u), zc);                                    \
      pre1 = MFMA(A1v, as_h8(CVUSE), q1);                                      \
      pre2 = MFMA(A2v, as_h8(CVUSE), q2);                                      \
    }                                                                          \
    if (DOPREF) { PREFDST = cvs[(col + 8 * dir + 1) * 64 + l]; }               \
    hc = elupack(a1, a2);                                                      \
    sign32 = bitL << 31;                                                       \
    col += dir;                                                                \
  }

#define elupack(a1, a2)                                                        \
  as_h8(uint4{pk2(elu1((a1)[0]), elu1((a1)[1])),                               \
              pk2(elu1((a1)[2]), elu1((a1)[3])),                               \
              pk2(elu1((a2)[0]), elu1((a2)[1])),                               \
              pk2(elu1((a2)[2]), elu1((a2)[3]))})

#define CHUNK(CU, CN)                                                          \
  STEP(CU[1], CN[0], true, true)                                               \
  STEP(CU[2], CN[1], true, true)                                               \
  STEP(CU[3], CN[2], true, true)                                               \
  STEP(CU[4], CN[3], true, true)                                               \
  STEP(CU[5], CN[4], true, true)                                               \
  STEP(CU[6], CN[5], true, true)                                               \
  STEP(CU[7], CN[6], true, true)                                               \
  STEP(CN[0], CN[7], true, true)

#define CHUNK_LAST(CU)                                                         \
  STEP(CU[1], cvDummy, false, true)                                            \
  STEP(CU[2], cvDummy, false, true)                                            \
  STEP(CU[3], cvDummy, false, true)                                            \
  STEP(CU[4], cvDummy, false, true)                                            \
  STEP(CU[5], cvDummy, false, true)                                            \
  STEP(CU[6], cvDummy, false, true)                                            \
  STEP(CU[7], cvDummy, false, true)                                            \
  STEP(CU[0], cvDummy, false, false)

#pragma unroll 1
        for (int cp = 0; cp < 3; ++cp) {
            CHUNK(cvA, cvB)          // even chunk
            CHUNK(cvB, cvA)          // odd chunk
        }
        CHUNK(cvA, cvB)              // chunk 6 (prefetches chunk 7 into cvB)
        CHUNK_LAST(cvB)              // chunk 7 (no prefetch; last step no pre)

        // row epilogue: out(63) + store state(63)
        {
            f32x4 od = MFMA(Awd, hc, dinit);
            const float du = __int_as_float(__float_as_int(od[0]) ^ sign32);
            logp -= __logf(1.f + __expf(du));
            cvs[(col - dir + 1) * 64 + l] = as_u4(hc);
        }
    }

    if (l < NB) out[bbase + l] = 0.5f * (logp + 64.f * Cterm);

#undef STEP
#undef CHUNK
#undef CHUNK_LAST
#undef elupack
}

} // namespace

extern "C" void kernel_launch(void* const* d_in, const int* in_sizes, int n_in,
                              void* d_out, int out_size, void* d_ws, size_t ws_size,
                              hipStream_t stream) {
    (void)n_in; (void)out_size; (void)d_ws; (void)ws_size;
    const int*   x    = (const int*)  d_in[0];
    const float* Win  = (const float*)d_in[1];
    const float* WcH  = (const float*)d_in[2];
    const float* WcV  = (const float*)d_in[3];
    const float* bV   = (const float*)d_in[4];
    const float* Wout = (const float*)d_in[5];
    const float* bout = (const float*)d_in[6];
    float*       out  = (float*)d_out;

    const int B = in_sizes[0] / (LSIDE * LSIDE);
    rnn2d_mfma5<<<B / NB, 64, 0, stream>>>(x, Win, WcH, WcV, bV, Wout, bout, out);
}

// Round 6
// 858.786 us; speedup vs baseline: 2.1618x; 1.2325x over previous
//
#include <hip/hip_runtime.h>
#include <cstdint>

namespace {

typedef _Float16 half_t;
typedef half_t half8  __attribute__((ext_vector_type(8)));
typedef __fp16 fp16x2 __attribute__((ext_vector_type(2)));
typedef float  f32x4  __attribute__((ext_vector_type(4)));

constexpr int LSIDE = 64;   // lattice side
constexpr int HID   = 32;   // hidden size
constexpr int NB    = 16;   // batch elements per block (MFMA N dim)

__device__ __forceinline__ half8 as_h8(uint4 u) { return __builtin_bit_cast(half8, u); }
__device__ __forceinline__ uint4 as_u4(half8 h) { return __builtin_bit_cast(uint4, h); }
__device__ __forceinline__ unsigned pk2(float a, float b) {
    fp16x2 t = __builtin_amdgcn_cvt_pkrtz(a, b);
    return __builtin_bit_cast(unsigned, t);
}
__device__ __forceinline__ float elu1(float v) {
    float e = __expf(v) - 1.f;
    return v > 0.f ? v : e;
}
__device__ __forceinline__ half8 elupack(const f32x4& a1, const f32x4& a2) {
    uint4 nb;
    nb.x = pk2(elu1(a1[0]), elu1(a1[1]));
    nb.y = pk2(elu1(a1[2]), elu1(a1[3]));
    nb.z = pk2(elu1(a2[0]), elu1(a2[1]));
    nb.w = pk2(elu1(a2[2]), elu1(a2[3]));
    return as_h8(nb);
}

#define MFMA(a,b,c) __builtin_amdgcn_mfma_f32_16x16x32_f16((a),(b),(c),0,0,0)

// MFMA layout (verified r3):
//   A: lane holds A[row=l&15][k=8*(l>>4)+e];  B: lane holds B[k=8*(l>>4)+e][col=l&15]
//   C: lane holds C[row=4*(l>>4)+c][col=l&15]
// A rows permuted so C of step s IS the B fragment of step s+1.

__global__ __launch_bounds__(128) void rnn2d_pipe(
    const int*   __restrict__ x,     // [B, 64, 64]
    const float* __restrict__ Win,   // [4, 32]
    const float* __restrict__ WcH,   // [32, 32]
    const float* __restrict__ WcV,   // [32, 32]
    const float* __restrict__ bV,    // [32]
    const float* __restrict__ Wout,  // [32, 2]
    const float* __restrict__ bout,  // [2]
    float*       __restrict__ out)   // [B]
{
    const int tid = threadIdx.x;
    const int wv  = tid >> 6;        // 0 = chain wave, 1 = helper wave
    const int l   = tid & 63;
    const int r_  = l & 15, g_ = l >> 4, n = l & 15;
    const int bbase = blockIdx.x * NB;

    __shared__ uint4 cvs[64 * 64];           // [phys col][lane] carries   (64 KB)
    __shared__ f32x4 ringF[4 * 8 * 64 * 2];  // [slot][i][lane][frag]      (64 KB)
    __shared__ unsigned sgnw[8 * 64];        // row-turn output signs       (2 KB)
    __shared__ float logpsh[64];

    for (int i = tid; i < 64 * 64; i += 128) cvs[i] = uint4{0u,0u,0u,0u};

    // ---- constant A fragments (both waves load; each uses a subset) ----
    const int j1 = 8 * (r_ >> 2) + (r_ & 3), j2 = j1 + 4;
    half8 A1h, A2h, A1v, A2v, A3a, A3b, Awd;
#pragma unroll
    for (int e = 0; e < 8; ++e) {
        const int k = 8 * g_ + e;
        A1h[e] = (half_t)WcH[k * HID + j1];
        A2h[e] = (half_t)WcH[k * HID + j2];
        A1v[e] = (half_t)WcV[k * HID + j1];
        A2v[e] = (half_t)WcV[k * HID + j2];
        float a3a = 0.f, a3b = 0.f;
        if (k < 4)       { a3a = Win[k * HID + j1]; a3b = Win[k * HID + j2]; }
        else if (k == 4) { a3a = bV[j1];            a3b = bV[j2]; }
        A3a[e] = (half_t)a3a;
        A3b[e] = (half_t)a3b;
        Awd[e] = (half_t)((r_ == 0) ? (Wout[k * 2 + 1] - Wout[k * 2 + 0]) : 0.f);
    }
    const float db = bout[1] - bout[0];
    f32x4 dinit; dinit[0]=db; dinit[1]=db; dinit[2]=db; dinit[3]=db;
    f32x4 zc;    zc[0]=0.f;  zc[1]=0.f;  zc[2]=0.f;  zc[3]=0.f;
    const unsigned gm16 = (g_ == 0) ? 0x3C00u : 0u;   // f16 1.0 selector

    const int* xw = x + (long)bbase * 4096;

    __syncthreads();   // cvs zeros visible

    // per-thread persistent state
    unsigned long long rmc = 0ull, rm1 = 0ull;  // wave1 masks: row rp / rp-1
    int xr[NB];
    float logp0 = 0.f, logp1 = 0.f;
    f32x4 Ua[4], Ub[4];                         // wave0 pre pipeline (const-indexed)
    half8 hc = as_h8(uint4{0u,0u,0u,0u});
    uint4 h7[8];                                // last-chunk states of prev row
#pragma unroll
    for (int i = 0; i < 8; ++i) h7[i] = uint4{0u,0u,0u,0u};

    if (wv == 1) {
        // ---- prologue: row-0 masks + ring chunks t=0 (q-only) and t=1 (full) ----
#pragma unroll
        for (int nn = 0; nn < NB; ++nn) xr[nn] = xw[nn * 4096 + l];
        {
            unsigned long long rm = 0ull;
#pragma unroll
            for (int nn = 0; nn < NB; ++nn) {
                unsigned long long bal = __ballot(xr[nn] == 1);
                rm = (n == nn) ? bal : rm;
            }
            rmc = rm;
        }
#pragma unroll
        for (int nn = 0; nn < NB; ++nn) xr[nn] = xw[nn * 4096 + 64 + l];

#pragma unroll
        for (int i = 0; i < 8; ++i) {           // t=0: q-only, row 0 chunk 0 (c = i)
            unsigned aP = 0u;
            if (i > 0) {
                unsigned bl = (unsigned)((rmc >> (i - 1)) & 1ull);
                aP = gm16 << (bl << 4);
            }
            uint4 b3u{aP, 0u, gm16, 0u};
            f32x4 q1 = MFMA(A3a, as_h8(b3u), zc);
            f32x4 q2 = MFMA(A3b, as_h8(b3u), zc);
            ringF[((0*8 + i)*64 + l)*2 + 0] = q1;
            ringF[((0*8 + i)*64 + l)*2 + 1] = q2;
        }
#pragma unroll
        for (int i = 0; i < 8; ++i) {           // t=1: full pre, row 0 chunk 1 (c = 8+i)
            const int c = 8 + i;
            unsigned bl = (unsigned)((rmc >> (c - 1)) & 1ull);
            unsigned aP = gm16 << (bl << 4);
            uint4 b3u{aP, 0u, gm16, 0u};
            f32x4 q1 = MFMA(A3a, as_h8(b3u), zc);
            f32x4 q2 = MFMA(A3b, as_h8(b3u), zc);
            half8 cvh = as_h8(cvs[c*64 + l]);   // zeros
            f32x4 p1 = MFMA(A1v, cvh, q1);
            f32x4 p2 = MFMA(A2v, cvh, q2);
            ringF[((1*8 + i)*64 + l)*2 + 0] = p1;
            ringF[((1*8 + i)*64 + l)*2 + 1] = p2;
        }
    }
    __syncthreads();

    if (wv == 0) {   // prime the rolling pre pipeline (scan pos 0,1,2)
        Ua[0] = ringF[((0*8+0)*64+l)*2+0]; Ub[0] = ringF[((0*8+0)*64+l)*2+1];
        Ua[1] = ringF[((0*8+1)*64+l)*2+0]; Ub[1] = ringF[((0*8+1)*64+l)*2+1];
        Ua[2] = ringF[((0*8+2)*64+l)*2+0]; Ub[2] = ringF[((0*8+2)*64+l)*2+1];
    }

    int c0 = 0, dir0 = 1;

#define PF(i)  { const int pf_=(i)+3; const int cs_=(gph+(pf_>>3))&3; const int ci_=pf_&7; \
                 Ua[((i)+3)&3] = ringF[((cs_*8+ci_)*64+l)*2+0];                            \
                 Ub[((i)+3)&3] = ringF[((cs_*8+ci_)*64+l)*2+1]; }

#define NORMAL(i) { PF(i)                                                                  \
      f32x4 a1 = MFMA(A1h, hc, Ua[(i)&3]); f32x4 a2 = MFMA(A2h, hc, Ub[(i)&3]);           \
      hc = elupack(a1, a2); cvs[c0*64+l] = as_u4(hc); c0 += dir0; }

#define NORM7(i) { PF(i)                                                                   \
      f32x4 a1 = MFMA(A1h, hc, Ua[(i)&3]); f32x4 a2 = MFMA(A2h, hc, Ub[(i)&3]);           \
      hc = elupack(a1, a2); cvs[c0*64+l] = as_u4(hc); h7[(i)] = as_u4(hc); c0 += dir0; }

#define SPECIAL(i) { PF(i)                                                                 \
      f32x4 pre1 = MFMA(A1v, as_h8(h7[7-(i)]), Ua[(i)&3]);                                 \
      f32x4 pre2 = MFMA(A2v, as_h8(h7[7-(i)]), Ub[(i)&3]);                                 \
      if (doOut) { f32x4 od = MFMA(Awd, as_h8(h7[7-(i)]), dinit);                          \
        float du = __int_as_float(__float_as_int(od[0]) ^ sgnw[(i)*64+l]);                 \
        logp0 -= __logf(1.f + __expf(du)); }                                               \
      f32x4 a1 = MFMA(A1h, hc, pre1); f32x4 a2 = MFMA(A2h, hc, pre2);                      \
      hc = elupack(a1, a2); cvs[c0*64+l] = as_u4(hc); c0 += dir0; }

    for (int gph = 0; gph < 512; ++gph) {
        const int k = gph & 7, rr = gph >> 3;
        if (wv == 0) {
            if (k == 0) {
                dir0 = (rr & 1) ? -1 : 1;
                c0   = (rr & 1) ? 63 : 0;
                hc   = as_h8(uint4{0u,0u,0u,0u});
                const bool doOut = (rr >= 1);
                SPECIAL(0) SPECIAL(1) SPECIAL(2) SPECIAL(3)
                SPECIAL(4) SPECIAL(5) SPECIAL(6) SPECIAL(7)
            } else if (k < 7) {
                NORMAL(0) NORMAL(1) NORMAL(2) NORMAL(3)
                NORMAL(4) NORMAL(5) NORMAL(6) NORMAL(7)
            } else {
                NORM7(0) NORM7(1) NORM7(2) NORM7(3)
                NORM7(4) NORM7(5) NORM7(6) NORM7(7)
            }
        } else {
            const int t = gph + 2;
            if (t < 512) {
                const int rp = t >> 3, kp = t & 7;
                const int dirp = (rp & 1) ? -1 : 1;
                if (kp == 0) {
                    // advance masks to row rp; prefetch row rp+1 spins
                    rm1 = rmc;
                    {
                        unsigned long long rm = 0ull;
#pragma unroll
                        for (int nn = 0; nn < NB; ++nn) {
                            unsigned long long bal = __ballot(xr[nn] == 1);
                            rm = (n == nn) ? bal : rm;
                        }
                        rmc = rm;
                    }
                    const int nr = (rp < 63) ? rp + 1 : 63;
#pragma unroll
                    for (int nn = 0; nn < NB; ++nn) xr[nn] = xw[nn * 4096 + nr * 64 + l];
                    // q-only build + signs for chunk (rp, 0)  [rp >= 1 here]
#pragma unroll
                    for (int i = 0; i < 8; ++i) {
                        const int c = (rp & 1) ? 63 - i : i;
                        unsigned aP = 0u;
                        if (i > 0) {
                            const int cl = c - dirp;
                            unsigned bl = (unsigned)((rmc >> cl) & 1ull);
                            aP = gm16 << (bl << 4);
                        }
                        unsigned bu = (unsigned)((rm1 >> c) & 1ull);
                        unsigned bP = gm16 << (bu << 4);
                        uint4 b3u{aP, bP, gm16, 0u};
                        f32x4 q1 = MFMA(A3a, as_h8(b3u), zc);
                        f32x4 q2 = MFMA(A3b, as_h8(b3u), zc);
                        const int slot = t & 3;
                        ringF[((slot*8 + i)*64 + l)*2 + 0] = q1;
                        ringF[((slot*8 + i)*64 + l)*2 + 1] = q2;
                        sgnw[i*64 + l] = bu << 31;
                    }
                } else {
                    const bool doOut = (rp >= 1);
#pragma unroll
                    for (int i = 0; i < 8; ++i) {
                        const int sg = 8 * kp + i;
                        const int c = (rp & 1) ? 63 - sg : sg;
                        half8 cvh = as_h8(cvs[c*64 + l]);    // row rp-1 carries
                        if (doOut) {
                            f32x4 od = MFMA(Awd, cvh, dinit);
                            unsigned s32 = (unsigned)((rm1 >> c) & 1ull) << 31;
                            float du = __int_as_float(__float_as_int(od[0]) ^ s32);
                            logp1 -= __logf(1.f + __expf(du));
                        }
                        const int cl = c - dirp;
                        unsigned bl = (unsigned)((rmc >> cl) & 1ull);
                        unsigned aP = gm16 << (bl << 4);
                        unsigned bP = 0u;
                        if (doOut) {
                            unsigned bu = (unsigned)((rm1 >> c) & 1ull);
                            bP = gm16 << (bu << 4);
                        }
                        uint4 b3u{aP, bP, gm16, 0u};
                        f32x4 q1 = MFMA(A3a, as_h8(b3u), zc);
                        f32x4 q2 = MFMA(A3b, as_h8(b3u), zc);
                        f32x4 p1 = MFMA(A1v, cvh, q1);
                        f32x4 p2 = MFMA(A2v, cvh, q2);
                        const int slot = t & 3;
                        ringF[((slot*8 + i)*64 + l)*2 + 0] = p1;
                        ringF[((slot*8 + i)*64 + l)*2 + 1] = p2;
                    }
                }
            }
        }
        __syncthreads();
    }

    if (wv == 0) logpsh[l] = logp0;
    __syncthreads();
    if (wv == 1) {
        // row-63 outputs (rmc holds row 63; cvs hold row 63 carries)
#pragma unroll 8
        for (int c = 0; c < 64; ++c) {
            half8 cvh = as_h8(cvs[c*64 + l]);
            f32x4 od = MFMA(Awd, cvh, dinit);
            unsigned s32 = (unsigned)((rmc >> c) & 1ull) << 31;
            float du = __int_as_float(__float_as_int(od[0]) ^ s32);
            logp1 -= __logf(1.f + __expf(du));
        }
        float tot = logp1 + logpsh[l];
        if (l < NB) out[bbase + n] = 0.5f * tot;
    }

#undef PF
#undef NORMAL
#undef NORM7
#undef SPECIAL
}

} // namespace

extern "C" void kernel_launch(void* const* d_in, const int* in_sizes, int n_in,
                              void* d_out, int out_size, void* d_ws, size_t ws_size,
                              hipStream_t stream) {
    (void)n_in; (void)out_size; (void)d_ws; (void)ws_size;
    const int*   x    = (const int*)  d_in[0];
    const float* Win  = (const float*)d_in[1];
    const float* WcH  = (const float*)d_in[2];
    const float* WcV  = (const float*)d_in[3];
    const float* bV   = (const float*)d_in[4];
    const float* Wout = (const float*)d_in[5];
    const float* bout = (const float*)d_in[6];
    float*       out  = (float*)d_out;

    const int B = in_sizes[0] / (LSIDE * LSIDE);
    rnn2d_pipe<<<B / NB, 128, 0, stream>>>(x, Win, WcH, WcV, bV, Wout, bout, out);
}

// Round 7
// 789.724 us; speedup vs baseline: 2.3508x; 1.0875x over previous
//
#include <hip/hip_runtime.h>
#include <cstdint>

namespace {

typedef _Float16 half_t;
typedef half_t half8  __attribute__((ext_vector_type(8)));
typedef __fp16 fp16x2 __attribute__((ext_vector_type(2)));
typedef float  f32x4  __attribute__((ext_vector_type(4)));

constexpr int LSIDE = 64;   // lattice side
constexpr int HID   = 32;   // hidden size
constexpr int NB    = 16;   // batch elements per block (MFMA N dim)

__device__ __forceinline__ half8 as_h8(uint4 u) { return __builtin_bit_cast(half8, u); }
__device__ __forceinline__ uint4 as_u4(half8 h) { return __builtin_bit_cast(uint4, h); }
__device__ __forceinline__ unsigned pk2(float a, float b) {
    fp16x2 t = __builtin_amdgcn_cvt_pkrtz(a, b);
    return __builtin_bit_cast(unsigned, t);
}
__device__ __forceinline__ float elu1(float v) {
    float e = __expf(v) - 1.f;
    return v > 0.f ? v : e;
}
__device__ __forceinline__ half8 elupack(const f32x4& a1, const f32x4& a2) {
    uint4 nb;
    nb.x = pk2(elu1(a1[0]), elu1(a1[1]));
    nb.y = pk2(elu1(a1[2]), elu1(a1[3]));
    nb.z = pk2(elu1(a2[0]), elu1(a2[1]));
    nb.w = pk2(elu1(a2[2]), elu1(a2[3]));
    return as_h8(nb);
}

#define MFMA(a,b,c) __builtin_amdgcn_mfma_f32_16x16x32_f16((a),(b),(c),0,0,0)

// MFMA layout (verified r3):
//   A: lane holds A[row=l&15][k=8*(l>>4)+e];  B: lane holds B[k=8*(l>>4)+e][col=l&15]
//   C: lane holds C[row=4*(l>>4)+c][col=l&15]
// A rows permuted so C of step s IS the B fragment of step s+1.

__global__ __launch_bounds__(192) void rnn2d_pipe3(
    const int*   __restrict__ x,     // [B, 64, 64]
    const float* __restrict__ Win,   // [4, 32]
    const float* __restrict__ WcH,   // [32, 32]
    const float* __restrict__ WcV,   // [32, 32]
    const float* __restrict__ bV,    // [32]
    const float* __restrict__ Wout,  // [32, 2]
    const float* __restrict__ bout,  // [2]
    float*       __restrict__ out)   // [B]
{
    const int tid = threadIdx.x;
    const int wv  = tid >> 6;        // 0 chain, 1 pre-build, 2 outputs
    const int l   = tid & 63;
    const int r_  = l & 15, g_ = l >> 4, n = l & 15;
    const int bbase = blockIdx.x * NB;

    __shared__ uint4 cvs[64 * 64];       // [phys col][lane] carries      (64 KB)
    __shared__ f32x4 ring1[4 * 8 * 64];  // [slot][i][lane] pre frag 1    (32 KB)
    __shared__ f32x4 ring2[4 * 8 * 64];  // [slot][i][lane] pre frag 2    (32 KB)
    __shared__ uint4 h7buf[8 * 64];      // row-turn states for wave2      (8 KB)

    for (int i = tid; i < 64 * 64; i += 192) cvs[i] = uint4{0u,0u,0u,0u};

    // ---- constant A fragments ----
    const int j1 = 8 * (r_ >> 2) + (r_ & 3), j2 = j1 + 4;
    half8 A1h, A2h, A1v, A2v, A3a, A3b, Awd;
#pragma unroll
    for (int e = 0; e < 8; ++e) {
        const int k = 8 * g_ + e;
        A1h[e] = (half_t)WcH[k * HID + j1];
        A2h[e] = (half_t)WcH[k * HID + j2];
        A1v[e] = (half_t)WcV[k * HID + j1];
        A2v[e] = (half_t)WcV[k * HID + j2];
        float a3a = 0.f, a3b = 0.f;
        if (k < 4)       { a3a = Win[k * HID + j1]; a3b = Win[k * HID + j2]; }
        else if (k == 4) { a3a = bV[j1];            a3b = bV[j2]; }
        A3a[e] = (half_t)a3a;
        A3b[e] = (half_t)a3b;
        Awd[e] = (half_t)((r_ == 0) ? (Wout[k * 2 + 1] - Wout[k * 2 + 0]) : 0.f);
    }
    const float db = bout[1] - bout[0];
    f32x4 dinit; dinit[0]=db; dinit[1]=db; dinit[2]=db; dinit[3]=db;
    f32x4 zc;    zc[0]=0.f;  zc[1]=0.f;  zc[2]=0.f;  zc[3]=0.f;
    const unsigned gm16 = (g_ == 0) ? 0x3C00u : 0u;   // f16 1.0 selector

    const int* xw = x + (long)bbase * 4096;

    __syncthreads();   // cvs zeros visible

    unsigned long long rmc = 0ull, rm1 = 0ull;
    int xr[NB];
    float logp = 0.f;
    f32x4 Ua[4], Ub[4];
    half8 hc = as_h8(uint4{0u,0u,0u,0u});
    uint4 h7[8];
#pragma unroll
    for (int i = 0; i < 8; ++i) h7[i] = uint4{0u,0u,0u,0u};

    if (wv >= 1) {   // both helper waves keep their own masks
#pragma unroll
        for (int nn = 0; nn < NB; ++nn) xr[nn] = xw[nn * 4096 + l];
        {
            unsigned long long rm = 0ull;
#pragma unroll
            for (int nn = 0; nn < NB; ++nn) {
                unsigned long long bal = __ballot(xr[nn] == 1);
                rm = (n == nn) ? bal : rm;
            }
            rmc = rm;
        }
#pragma unroll
        for (int nn = 0; nn < NB; ++nn) xr[nn] = xw[nn * 4096 + 64 + l];
    }

    if (wv == 1) {
        // ring t=0 (q-only; wave0 adds A1v*h7(=0)) and t=1 (cv=0 so p==q)
#pragma unroll
        for (int i = 0; i < 8; ++i) {
            unsigned aP = 0u;
            if (i > 0) {
                unsigned bl = (unsigned)((rmc >> (i - 1)) & 1ull);
                aP = gm16 << (bl << 4);
            }
            uint4 b3u{aP, 0u, gm16, 0u};
            ring1[(0*8 + i)*64 + l] = MFMA(A3a, as_h8(b3u), zc);
            ring2[(0*8 + i)*64 + l] = MFMA(A3b, as_h8(b3u), zc);
        }
#pragma unroll
        for (int i = 0; i < 8; ++i) {
            const int c = 8 + i;
            unsigned bl = (unsigned)((rmc >> (c - 1)) & 1ull);
            unsigned aP = gm16 << (bl << 4);
            uint4 b3u{aP, 0u, gm16, 0u};
            ring1[(1*8 + i)*64 + l] = MFMA(A3a, as_h8(b3u), zc);
            ring2[(1*8 + i)*64 + l] = MFMA(A3b, as_h8(b3u), zc);
        }
    }
    __syncthreads();

    if (wv == 0) {
        Ua[0] = ring1[0*64+l]; Ub[0] = ring2[0*64+l];
        Ua[1] = ring1[1*64+l]; Ub[1] = ring2[1*64+l];
        Ua[2] = ring1[2*64+l]; Ub[2] = ring2[2*64+l];
    }

    int c0 = 0, dir0 = 1;

#define PF(i)  { const int pf_=(i)+3; const int cs_=(gph+(pf_>>3))&3; const int ci_=pf_&7; \
                 Ua[((i)+3)&3] = ring1[(cs_*8+ci_)*64+l];                                  \
                 Ub[((i)+3)&3] = ring2[(cs_*8+ci_)*64+l]; }

#define NORMAL(i) { PF(i)                                                                  \
      f32x4 a1 = MFMA(A1h, hc, Ua[(i)&3]); f32x4 a2 = MFMA(A2h, hc, Ub[(i)&3]);           \
      hc = elupack(a1, a2); cvs[c0*64+l] = as_u4(hc); c0 += dir0; }

#define NORM7(i) { PF(i)                                                                   \
      f32x4 a1 = MFMA(A1h, hc, Ua[(i)&3]); f32x4 a2 = MFMA(A2h, hc, Ub[(i)&3]);           \
      hc = elupack(a1, a2); { uint4 u_ = as_u4(hc); cvs[c0*64+l] = u_; h7[(i)] = u_;      \
      h7buf[(i)*64+l] = u_; } c0 += dir0; }

#define SPECIAL(i) { PF(i)                                                                 \
      f32x4 p1 = MFMA(A1v, as_h8(h7[7-(i)]), Ua[(i)&3]);                                   \
      f32x4 p2 = MFMA(A2v, as_h8(h7[7-(i)]), Ub[(i)&3]);                                   \
      f32x4 a1 = MFMA(A1h, hc, p1); f32x4 a2 = MFMA(A2h, hc, p2);                          \
      hc = elupack(a1, a2); cvs[c0*64+l] = as_u4(hc); c0 += dir0; }

    for (int gph = 0; gph < 512; ++gph) {
        if (wv == 0) {
            const int k = gph & 7, rr = gph >> 3;
            if (k == 0) {
                dir0 = (rr & 1) ? -1 : 1;
                c0   = (rr & 1) ? 63 : 0;
                hc   = as_h8(uint4{0u,0u,0u,0u});
                SPECIAL(0) SPECIAL(1) SPECIAL(2) SPECIAL(3)
                SPECIAL(4) SPECIAL(5) SPECIAL(6) SPECIAL(7)
            } else if (k < 7) {
                NORMAL(0) NORMAL(1) NORMAL(2) NORMAL(3)
                NORMAL(4) NORMAL(5) NORMAL(6) NORMAL(7)
            } else {
                NORM7(0) NORM7(1) NORM7(2) NORM7(3)
                NORM7(4) NORM7(5) NORM7(6) NORM7(7)
            }
        } else if (wv == 1) {
            const int t = gph + 2;
            if (t < 512) {
                const int rp = t >> 3, kp = t & 7;
                const int dirp = (rp & 1) ? -1 : 1;
                const int slot = t & 3;
                if (kp == 0) {
                    rm1 = rmc;
                    {
                        unsigned long long rm = 0ull;
#pragma unroll
                        for (int nn = 0; nn < NB; ++nn) {
                            unsigned long long bal = __ballot(xr[nn] == 1);
                            rm = (n == nn) ? bal : rm;
                        }
                        rmc = rm;
                    }
                    const int nr = (rp < 63) ? rp + 1 : 63;
#pragma unroll
                    for (int nn = 0; nn < NB; ++nn) xr[nn] = xw[nn * 4096 + nr * 64 + l];
#pragma unroll
                    for (int i = 0; i < 8; ++i) {       // q-only chunk (turn)
                        const int c = (rp & 1) ? 63 - i : i;
                        unsigned aP = 0u;
                        if (i > 0) {
                            unsigned bl = (unsigned)((rmc >> (c - dirp)) & 1ull);
                            aP = gm16 << (bl << 4);
                        }
                        unsigned bu = (unsigned)((rm1 >> c) & 1ull);
                        unsigned bP = gm16 << (bu << 4);
                        uint4 b3u{aP, bP, gm16, 0u};
                        ring1[(slot*8 + i)*64 + l] = MFMA(A3a, as_h8(b3u), zc);
                        ring2[(slot*8 + i)*64 + l] = MFMA(A3b, as_h8(b3u), zc);
                    }
                } else {
#pragma unroll
                    for (int i = 0; i < 8; ++i) {       // full pre
                        const int sg = 8 * kp + i;
                        const int c = (rp & 1) ? 63 - sg : sg;
                        half8 cvh = as_h8(cvs[c*64 + l]);
                        unsigned bl = (unsigned)((rmc >> (c - dirp)) & 1ull);
                        unsigned aP = gm16 << (bl << 4);
                        unsigned bP = 0u;
                        if (rp >= 1) {
                            unsigned bu = (unsigned)((rm1 >> c) & 1ull);
                            bP = gm16 << (bu << 4);
                        }
                        uint4 b3u{aP, bP, gm16, 0u};
                        f32x4 q1 = MFMA(A3a, as_h8(b3u), zc);
                        f32x4 q2 = MFMA(A3b, as_h8(b3u), zc);
                        ring1[(slot*8 + i)*64 + l] = MFMA(A1v, cvh, q1);
                        ring2[(slot*8 + i)*64 + l] = MFMA(A2v, cvh, q2);
                    }
                }
            }
        } else {
            const int t = gph + 2;
            if (t < 512) {
                const int rp = t >> 3, kp = t & 7;
                if (kp == 0) {
                    rm1 = rmc;
                    {
                        unsigned long long rm = 0ull;
#pragma unroll
                        for (int nn = 0; nn < NB; ++nn) {
                            unsigned long long bal = __ballot(xr[nn] == 1);
                            rm = (n == nn) ? bal : rm;
                        }
                        rmc = rm;
                    }
                    const int nr = (rp < 63) ? rp + 1 : 63;
#pragma unroll
                    for (int nn = 0; nn < NB; ++nn) xr[nn] = xw[nn * 4096 + nr * 64 + l];
                } else if (rp >= 1) {
                    f32x4 odv[8];
#pragma unroll
                    for (int i = 0; i < 8; ++i) {       // batch the MFMAs
                        const int sg = 8 * kp + i;
                        const int c = (rp & 1) ? 63 - sg : sg;
                        odv[i] = MFMA(Awd, as_h8(cvs[c*64 + l]), dinit);
                    }
#pragma unroll
                    for (int i = 0; i < 8; ++i) {       // softplus after latency
                        const int sg = 8 * kp + i;
                        const int c = (rp & 1) ? 63 - sg : sg;
                        unsigned s32 = (unsigned)((rm1 >> c) & 1ull) << 31;
                        float du = __int_as_float(__float_as_int(odv[i][0]) ^ s32);
                        logp -= __logf(1.f + __expf(du));
                    }
                    if (kp == 2) {                      // row rp-1 turn outputs
                        f32x4 odt[8];
#pragma unroll
                        for (int i = 0; i < 8; ++i)
                            odt[i] = MFMA(Awd, as_h8(h7buf[i*64 + l]), dinit);
#pragma unroll
                        for (int i = 0; i < 8; ++i) {
                            const int c = ((rp - 1) & 1) ? 7 - i : 56 + i;
                            unsigned s32 = (unsigned)((rm1 >> c) & 1ull) << 31;
                            float du = __int_as_float(__float_as_int(odt[i][0]) ^ s32);
                            logp -= __logf(1.f + __expf(du));
                        }
                    }
                }
            }
        }
        __syncthreads();
    }

    if (wv == 2) {
        // row-63 outputs: rmc holds row 63; cvs hold row 63 carries
#pragma unroll 8
        for (int c = 0; c < 64; ++c) {
            f32x4 od = MFMA(Awd, as_h8(cvs[c*64 + l]), dinit);
            unsigned s32 = (unsigned)((rmc >> c) & 1ull) << 31;
            float du = __int_as_float(__float_as_int(od[0]) ^ s32);
            logp -= __logf(1.f + __expf(du));
        }
        if (l < NB) out[bbase + n] = 0.5f * logp;
    }

#undef PF
#undef NORMAL
#undef NORM7
#undef SPECIAL
}

} // namespace

extern "C" void kernel_launch(void* const* d_in, const int* in_sizes, int n_in,
                              void* d_out, int out_size, void* d_ws, size_t ws_size,
                              hipStream_t stream) {
    (void)n_in; (void)out_size; (void)d_ws; (void)ws_size;
    const int*   x    = (const int*)  d_in[0];
    const float* Win  = (const float*)d_in[1];
    const float* WcH  = (const float*)d_in[2];
    const float* WcV  = (const float*)d_in[3];
    const float* bV   = (const float*)d_in[4];
    const float* Wout = (const float*)d_in[5];
    const float* bout = (const float*)d_in[6];
    float*       out  = (float*)d_out;

    const int B = in_sizes[0] / (LSIDE * LSIDE);
    rnn2d_pipe3<<<B / NB, 192, 0, stream>>>(x, Win, WcH, WcV, bV, Wout, bout, out);
}

// Round 8
// 744.783 us; speedup vs baseline: 2.4927x; 1.0603x over previous
//
#include <hip/hip_runtime.h>
#include <cstdint>

namespace {

typedef _Float16 half_t;
typedef half_t half8  __attribute__((ext_vector_type(8)));
typedef __fp16 fp16x2 __attribute__((ext_vector_type(2)));
typedef float  f32x4  __attribute__((ext_vector_type(4)));

constexpr int LSIDE = 64;   // lattice side
constexpr int HID   = 32;   // hidden size
constexpr int NB    = 16;   // batch elements per block (MFMA N dim)
constexpr float LOG2E = 1.4426950408889634f;
constexpr float LN2   = 0.6931471805599453f;

__device__ __forceinline__ half8 as_h8(uint4 u) { return __builtin_bit_cast(half8, u); }
__device__ __forceinline__ uint4 as_u4(half8 h) { return __builtin_bit_cast(uint4, h); }
__device__ __forceinline__ unsigned pk2(float a, float b) {
    fp16x2 t = __builtin_amdgcn_cvt_pkrtz(a, b);
    return __builtin_bit_cast(unsigned, t);
}

// acc is log2e-scaled pre-activation z*log2e. Returns s1 = elu(z)+1 packed f16.
// s1 = max(z,0) + exp(min(z,0)) = ln2*max(acc,0) + exp2(min(acc,0)).
// Branch-free, no vcc, 4 ops/elem, stage-parallel across 8 elems.
__device__ __forceinline__ half8 elupack2(const f32x4& a1, const f32x4& a2) {
    float m[8], w[8], e[8], s[8];
#pragma unroll
    for (int i = 0; i < 4; ++i) { m[i]   = fmaxf(a1[i], 0.f); w[i]   = fminf(a1[i], 0.f); }
#pragma unroll
    for (int i = 0; i < 4; ++i) { m[4+i] = fmaxf(a2[i], 0.f); w[4+i] = fminf(a2[i], 0.f); }
#pragma unroll
    for (int i = 0; i < 8; ++i) e[i] = __builtin_amdgcn_exp2f(w[i]);
#pragma unroll
    for (int i = 0; i < 8; ++i) s[i] = fmaf(m[i], LN2, e[i]);
    uint4 nb;
    nb.x = pk2(s[0], s[1]); nb.y = pk2(s[2], s[3]);
    nb.z = pk2(s[4], s[5]); nb.w = pk2(s[6], s[7]);
    return as_h8(nb);
}

#define MFMA(a,b,c) __builtin_amdgcn_mfma_f32_16x16x32_f16((a),(b),(c),0,0,0)

// MFMA layout (verified r3):
//   A: lane holds A[row=l&15][k=8*(l>>4)+e];  B: lane holds B[k=8*(l>>4)+e][col=l&15]
//   C: lane holds C[row=4*(l>>4)+c][col=l&15]
// A rows permuted so C of step s IS the B fragment of step s+1.
// States stored as s1 = h+1 (f16). Weight row-sums folded into bias; recurrent
// weights pre-scaled by log2e so ELU's exp needs no multiply.

__global__ __launch_bounds__(192) void rnn2d_pipe4(
    const int*   __restrict__ x,     // [B, 64, 64]
    const float* __restrict__ Win,   // [4, 32]
    const float* __restrict__ WcH,   // [32, 32]
    const float* __restrict__ WcV,   // [32, 32]
    const float* __restrict__ bV,    // [32]
    const float* __restrict__ Wout,  // [32, 2]
    const float* __restrict__ bout,  // [2]
    float*       __restrict__ out)   // [B]
{
    const int tid = threadIdx.x;
    const int wv  = tid >> 6;        // 0 chain, 1 pre-build, 2 outputs
    const int l   = tid & 63;
    const int r_  = l & 15, g_ = l >> 4, n = l & 15;
    const int bbase = blockIdx.x * NB;

    __shared__ uint4 cvs[64 * 64];       // [phys col][lane] s1-carries   (64 KB)
    __shared__ f32x4 ring1[4 * 8 * 64];  // [slot][i][lane] pre frag 1    (32 KB)
    __shared__ f32x4 ring2[4 * 8 * 64];  // [slot][i][lane] pre frag 2    (32 KB)
    __shared__ uint4 h7buf[8 * 64];      // row-turn states for wave2      (8 KB)

    const uint4 ONES4{0x3C003C00u, 0x3C003C00u, 0x3C003C00u, 0x3C003C00u}; // f16 1.0 x8
    for (int i = tid; i < 64 * 64; i += 192) cvs[i] = ONES4;   // s1(row -1) = 1

    // ---- constant A fragments (log2e-scaled; bias has row-sum compensation) ----
    const int j1 = 8 * (r_ >> 2) + (r_ & 3), j2 = j1 + 4;
    float rsH1 = 0.f, rsH2 = 0.f, rsV1 = 0.f, rsV2 = 0.f;
#pragma unroll
    for (int k = 0; k < HID; ++k) {
        rsH1 += WcH[k * HID + j1]; rsH2 += WcH[k * HID + j2];
        rsV1 += WcV[k * HID + j1]; rsV2 += WcV[k * HID + j2];
    }
    half8 A1h, A2h, A1v, A2v, A3a, A3b, Awd;
#pragma unroll
    for (int e = 0; e < 8; ++e) {
        const int k = 8 * g_ + e;
        A1h[e] = (half_t)(LOG2E * WcH[k * HID + j1]);
        A2h[e] = (half_t)(LOG2E * WcH[k * HID + j2]);
        A1v[e] = (half_t)(LOG2E * WcV[k * HID + j1]);
        A2v[e] = (half_t)(LOG2E * WcV[k * HID + j2]);
        float a3a = 0.f, a3b = 0.f;
        if (k < 4)       { a3a = Win[k * HID + j1]; a3b = Win[k * HID + j2]; }
        else if (k == 4) { a3a = bV[j1] - rsH1 - rsV1;  // h = s1-1 compensation
                           a3b = bV[j2] - rsH2 - rsV2; }
        A3a[e] = (half_t)(LOG2E * a3a);
        A3b[e] = (half_t)(LOG2E * a3b);
        Awd[e] = (half_t)((r_ == 0) ? (Wout[k * 2 + 1] - Wout[k * 2 + 0]) : 0.f);
    }
    float sAwd = 0.f;
#pragma unroll
    for (int k = 0; k < HID; ++k) sAwd += Wout[k * 2 + 1] - Wout[k * 2 + 0];
    const float db = bout[1] - bout[0] - sAwd;           // Awd*(s1-1) compensation
    f32x4 dinit; dinit[0]=db; dinit[1]=db; dinit[2]=db; dinit[3]=db;
    f32x4 zc;    zc[0]=0.f;  zc[1]=0.f;  zc[2]=0.f;  zc[3]=0.f;
    const unsigned gm16 = (g_ == 0) ? 0x3C00u : 0u;   // f16 1.0 selector

    const int* xw = x + (long)bbase * 4096;

    __syncthreads();   // cvs init visible

    unsigned long long rmc = 0ull, rm1 = 0ull;
    int xr[NB];
    float logp = 0.f;
    f32x4 Ua[4], Ub[4];
    half8 hc = as_h8(ONES4);
    uint4 h7[8];
#pragma unroll
    for (int i = 0; i < 8; ++i) h7[i] = ONES4;

    if (wv >= 1) {   // both helper waves keep their own masks
#pragma unroll
        for (int nn = 0; nn < NB; ++nn) xr[nn] = xw[nn * 4096 + l];
        {
            unsigned long long rm = 0ull;
#pragma unroll
            for (int nn = 0; nn < NB; ++nn) {
                unsigned long long bal = __ballot(xr[nn] == 1);
                rm = (n == nn) ? bal : rm;
            }
            rmc = rm;
        }
#pragma unroll
        for (int nn = 0; nn < NB; ++nn) xr[nn] = xw[nn * 4096 + 64 + l];
    }

    if (wv == 1) {
        // ring t=0 (q-only; wave0 adds A1v*h7(=1)) and t=1 (cv=1: A1v*1 cancels rsV)
#pragma unroll
        for (int i = 0; i < 8; ++i) {
            unsigned aP = 0u;
            if (i > 0) {
                unsigned bl = (unsigned)((rmc >> (i - 1)) & 1ull);
                aP = gm16 << (bl << 4);
            }
            uint4 b3u{aP, 0u, gm16, 0u};
            ring1[(0*8 + i)*64 + l] = MFMA(A3a, as_h8(b3u), zc);
            ring2[(0*8 + i)*64 + l] = MFMA(A3b, as_h8(b3u), zc);
        }
#pragma unroll
        for (int i = 0; i < 8; ++i) {
            const int c = 8 + i;
            unsigned bl = (unsigned)((rmc >> (c - 1)) & 1ull);
            unsigned aP = gm16 << (bl << 4);
            uint4 b3u{aP, 0u, gm16, 0u};
            f32x4 q1 = MFMA(A3a, as_h8(b3u), zc);
            f32x4 q2 = MFMA(A3b, as_h8(b3u), zc);
            half8 cvh = as_h8(cvs[c*64 + l]);   // ones
            ring1[(1*8 + i)*64 + l] = MFMA(A1v, cvh, q1);
            ring2[(1*8 + i)*64 + l] = MFMA(A2v, cvh, q2);
        }
    }
    __syncthreads();

    if (wv == 0) {
        Ua[0] = ring1[0*64+l]; Ub[0] = ring2[0*64+l];
        Ua[1] = ring1[1*64+l]; Ub[1] = ring2[1*64+l];
        Ua[2] = ring1[2*64+l]; Ub[2] = ring2[2*64+l];
    }

    int c0 = 0, dir0 = 1;

#define PF(i)  { const int pf_=(i)+3; const int cs_=(gph+(pf_>>3))&3; const int ci_=pf_&7; \
                 Ua[((i)+3)&3] = ring1[(cs_*8+ci_)*64+l];                                  \
                 Ub[((i)+3)&3] = ring2[(cs_*8+ci_)*64+l]; }

#define NORMAL(i) { PF(i)                                                                  \
      f32x4 a1 = MFMA(A1h, hc, Ua[(i)&3]); f32x4 a2 = MFMA(A2h, hc, Ub[(i)&3]);           \
      hc = elupack2(a1, a2); cvs[c0*64+l] = as_u4(hc); c0 += dir0; }

#define NORM7(i) { PF(i)                                                                   \
      f32x4 a1 = MFMA(A1h, hc, Ua[(i)&3]); f32x4 a2 = MFMA(A2h, hc, Ub[(i)&3]);           \
      hc = elupack2(a1, a2); { uint4 u_ = as_u4(hc); cvs[c0*64+l] = u_; h7[(i)] = u_;     \
      h7buf[(i)*64+l] = u_; } c0 += dir0; }

#define SPECIAL(i) { PF(i)                                                                 \
      f32x4 p1 = MFMA(A1v, as_h8(h7[7-(i)]), Ua[(i)&3]);                                   \
      f32x4 p2 = MFMA(A2v, as_h8(h7[7-(i)]), Ub[(i)&3]);                                   \
      f32x4 a1 = MFMA(A1h, hc, p1); f32x4 a2 = MFMA(A2h, hc, p2);                          \
      hc = elupack2(a1, a2); cvs[c0*64+l] = as_u4(hc); c0 += dir0; }

    for (int gph = 0; gph < 512; ++gph) {
        if (wv == 0) {
            const int k = gph & 7, rr = gph >> 3;
            if (k == 0) {
                dir0 = (rr & 1) ? -1 : 1;
                c0   = (rr & 1) ? 63 : 0;
                hc   = as_h8(ONES4);          // h=0 -> s1=1
                SPECIAL(0) SPECIAL(1) SPECIAL(2) SPECIAL(3)
                SPECIAL(4) SPECIAL(5) SPECIAL(6) SPECIAL(7)
            } else if (k < 7) {
                NORMAL(0) NORMAL(1) NORMAL(2) NORMAL(3)
                NORMAL(4) NORMAL(5) NORMAL(6) NORMAL(7)
            } else {
                NORM7(0) NORM7(1) NORM7(2) NORM7(3)
                NORM7(4) NORM7(5) NORM7(6) NORM7(7)
            }
        } else if (wv == 1) {
            const int t = gph + 2;
            if (t < 512) {
                const int rp = t >> 3, kp = t & 7;
                const int dirp = (rp & 1) ? -1 : 1;
                const int slot = t & 3;
                if (kp == 0) {
                    rm1 = rmc;
                    {
                        unsigned long long rm = 0ull;
#pragma unroll
                        for (int nn = 0; nn < NB; ++nn) {
                            unsigned long long bal = __ballot(xr[nn] == 1);
                            rm = (n == nn) ? bal : rm;
                        }
                        rmc = rm;
                    }
                    const int nr = (rp < 63) ? rp + 1 : 63;
#pragma unroll
                    for (int nn = 0; nn < NB; ++nn) xr[nn] = xw[nn * 4096 + nr * 64 + l];
#pragma unroll
                    for (int i = 0; i < 8; ++i) {       // q-only chunk (turn)
                        const int c = (rp & 1) ? 63 - i : i;
                        unsigned aP = 0u;
                        if (i > 0) {
                            unsigned bl = (unsigned)((rmc >> (c - dirp)) & 1ull);
                            aP = gm16 << (bl << 4);
                        }
                        unsigned bu = (unsigned)((rm1 >> c) & 1ull);
                        unsigned bP = gm16 << (bu << 4);
                        uint4 b3u{aP, bP, gm16, 0u};
                        ring1[(slot*8 + i)*64 + l] = MFMA(A3a, as_h8(b3u), zc);
                        ring2[(slot*8 + i)*64 + l] = MFMA(A3b, as_h8(b3u), zc);
                    }
                } else {
#pragma unroll
                    for (int i = 0; i < 8; ++i) {       // full pre
                        const int sg = 8 * kp + i;
                        const int c = (rp & 1) ? 63 - sg : sg;
                        half8 cvh = as_h8(cvs[c*64 + l]);
                        unsigned bl = (unsigned)((rmc >> (c - dirp)) & 1ull);
                        unsigned aP = gm16 << (bl << 4);
                        unsigned bP = 0u;
                        if (rp >= 1) {
                            unsigned bu = (unsigned)((rm1 >> c) & 1ull);
                            bP = gm16 << (bu << 4);
                        }
                        uint4 b3u{aP, bP, gm16, 0u};
                        f32x4 q1 = MFMA(A3a, as_h8(b3u), zc);
                        f32x4 q2 = MFMA(A3b, as_h8(b3u), zc);
                        ring1[(slot*8 + i)*64 + l] = MFMA(A1v, cvh, q1);
                        ring2[(slot*8 + i)*64 + l] = MFMA(A2v, cvh, q2);
                    }
                }
            }
        } else {
            const int t = gph + 2;
            if (t < 512) {
                const int rp = t >> 3, kp = t & 7;
                if (kp == 0) {
                    rm1 = rmc;
                    {
                        unsigned long long rm = 0ull;
#pragma unroll
                        for (int nn = 0; nn < NB; ++nn) {
                            unsigned long long bal = __ballot(xr[nn] == 1);
                            rm = (n == nn) ? bal : rm;
                        }
                        rmc = rm;
                    }
                    const int nr = (rp < 63) ? rp + 1 : 63;
#pragma unroll
                    for (int nn = 0; nn < NB; ++nn) xr[nn] = xw[nn * 4096 + nr * 64 + l];
                } else if (rp >= 1) {
                    f32x4 odv[8];
#pragma unroll
                    for (int i = 0; i < 8; ++i) {       // batch the MFMAs
                        const int sg = 8 * kp + i;
                        const int c = (rp & 1) ? 63 - sg : sg;
                        odv[i] = MFMA(Awd, as_h8(cvs[c*64 + l]), dinit);
                    }
#pragma unroll
                    for (int i = 0; i < 8; ++i) {       // softplus after latency
                        const int sg = 8 * kp + i;
                        const int c = (rp & 1) ? 63 - sg : sg;
                        unsigned s32 = (unsigned)((rm1 >> c) & 1ull) << 31;
                        float du = __int_as_float(__float_as_int(odv[i][0]) ^ s32);
                        logp -= __logf(1.f + __expf(du));
                    }
                    if (kp == 2) {                      // row rp-1 turn outputs
                        f32x4 odt[8];
#pragma unroll
                        for (int i = 0; i < 8; ++i)
                            odt[i] = MFMA(Awd, as_h8(h7buf[i*64 + l]), dinit);
#pragma unroll
                        for (int i = 0; i < 8; ++i) {
                            const int c = ((rp - 1) & 1) ? 7 - i : 56 + i;
                            unsigned s32 = (unsigned)((rm1 >> c) & 1ull) << 31;
                            float du = __int_as_float(__float_as_int(odt[i][0]) ^ s32);
                            logp -= __logf(1.f + __expf(du));
                        }
                    }
                }
            }
        }
        __syncthreads();
    }

    if (wv == 2) {
        // row-63 outputs: rmc holds row 63; cvs hold row 63 carries
#pragma unroll 8
        for (int c = 0; c < 64; ++c) {
            f32x4 od = MFMA(Awd, as_h8(cvs[c*64 + l]), dinit);
            unsigned s32 = (unsigned)((rmc >> c) & 1ull) << 31;
            float du = __int_as_float(__float_as_int(od[0]) ^ s32);
            logp -= __logf(1.f + __expf(du));
        }
        if (l < NB) out[bbase + n] = 0.5f * logp;
    }

#undef PF
#undef NORMAL
#undef NORM7
#undef SPECIAL
}

} // namespace

extern "C" void kernel_launch(void* const* d_in, const int* in_sizes, int n_in,
                              void* d_out, int out_size, void* d_ws, size_t ws_size,
                              hipStream_t stream) {
    (void)n_in; (void)out_size; (void)d_ws; (void)ws_size;
    const int*   x    = (const int*)  d_in[0];
    const float* Win  = (const float*)d_in[1];
    const float* WcH  = (const float*)d_in[2];
    const float* WcV  = (const float*)d_in[3];
    const float* bV   = (const float*)d_in[4];
    const float* Wout = (const float*)d_in[5];
    const float* bout = (const float*)d_in[6];
    float*       out  = (float*)d_out;

    const int B = in_sizes[0] / (LSIDE * LSIDE);
    rnn2d_pipe4<<<B / NB, 192, 0, stream>>>(x, Win, WcH, WcV, bV, Wout, bout, out);
}